// Round 7
// baseline (399.751 us; speedup 1.0000x reference)
//
#include <hip/hip_runtime.h>
#include <hip/hip_bf16.h>

#define BB 512
#define TT 128

typedef unsigned short u16;
typedef short v8s __attribute__((ext_vector_type(8)));
typedef float f32x4 __attribute__((ext_vector_type(4)));

#define L2E  1.4426950408889634f
#define L2E2 2.8853900817779268f

__device__ __forceinline__ u16 f2bf(float x){
  union { float f; unsigned int u; } v; v.f = x;
  unsigned int r = (v.u + 0x7fffu + ((v.u >> 16) & 1u)) >> 16;
  return (u16)r;
}
__device__ __forceinline__ float lo_bits(unsigned u){
  union { unsigned int i; float f; } v; v.i = u << 16; return v.f;
}
__device__ __forceinline__ float hi_bits(unsigned u){
  union { unsigned int i; float f; } v; v.i = u & 0xffff0000u; return v.f;
}
// fast bf16 pack: RNE, matches f2bf
__device__ __forceinline__ uint2 pack4(f32x4 a){
  uint2 r;
  asm("v_cvt_pk_bf16_f32 %0, %1, %2" : "=v"(r.x) : "v"(a[0]), "v"(a[1]));
  asm("v_cvt_pk_bf16_f32 %0, %1, %2" : "=v"(r.y) : "v"(a[2]), "v"(a[3]));
  return r;
}
__device__ __forceinline__ float rcp_f(float x){ return __builtin_amdgcn_rcpf(x); }
__device__ __forceinline__ float exp2_f(float x){
  float r; asm("v_exp_f32 %0, %1" : "=v"(r) : "v"(x)); return r;
}
// inputs prescaled by log2e (i,f,o) and 2*log2e (g)
__device__ __forceinline__ float sigm2(float y){ return rcp_f(1.f + exp2_f(-y)); }
__device__ __forceinline__ float tanh2(float y){ return fmaf(2.f, sigm2(y), -1.f); }

// encoder-only (unscaled) helpers
__device__ __forceinline__ float tanh_f(float x){
  float e = __expf(-2.f * fabsf(x));
  float r = (1.f - e) * rcp_f(1.f + e);
  return copysignf(r, x);
}
// barrier that waits only LDS ops: global stores/loads stay in flight.
// AGPR clobbers: forbid compiler VGPR->AGPR stashing across iterations.
#define AGCLOB "a0","a1","a2","a3","a4","a5","a6","a7","a8","a9","a10","a11","a12","a13","a14","a15", \
  "a16","a17","a18","a19","a20","a21","a22","a23","a24","a25","a26","a27","a28","a29","a30","a31", \
  "a32","a33","a34","a35","a36","a37","a38","a39","a40","a41","a42","a43","a44","a45","a46","a47", \
  "a48","a49","a50","a51","a52","a53","a54","a55","a56","a57","a58","a59","a60","a61","a62","a63"
__device__ __forceinline__ void bar_lds(){
  __builtin_amdgcn_sched_barrier(0);
  asm volatile("s_waitcnt lgkmcnt(0)" ::: "memory");
  __builtin_amdgcn_s_barrier();
  __builtin_amdgcn_sched_barrier(0);
}

// write one 16B weight fragment (4 VGPRs) into hardcoded AGPR quad
#define LOADW(PTR, Q, KF, A0, A1, A2, A3) { \
  f32x4 wq_ = *(const f32x4*)((PTR) + (size_t)(((w + 8*(Q))*4 + (KF))*64 + l)*8); \
  asm volatile("v_accvgpr_write_b32 " A0 ", %0\n\t" \
               "v_accvgpr_write_b32 " A1 ", %1\n\t" \
               "v_accvgpr_write_b32 " A2 ", %2\n\t" \
               "v_accvgpr_write_b32 " A3 ", %3" \
               :: "v"(wq_[0]), "v"(wq_[1]), "v"(wq_[2]), "v"(wq_[3]) : A0, A1, A2, A3); }

#define LOADW_ALL(PTR) \
  LOADW(PTR,0,0,"a0","a1","a2","a3")   LOADW(PTR,0,1,"a4","a5","a6","a7") \
  LOADW(PTR,0,2,"a8","a9","a10","a11") LOADW(PTR,0,3,"a12","a13","a14","a15") \
  LOADW(PTR,1,0,"a16","a17","a18","a19") LOADW(PTR,1,1,"a20","a21","a22","a23") \
  LOADW(PTR,1,2,"a24","a25","a26","a27") LOADW(PTR,1,3,"a28","a29","a30","a31") \
  LOADW(PTR,2,0,"a32","a33","a34","a35") LOADW(PTR,2,1,"a36","a37","a38","a39") \
  LOADW(PTR,2,2,"a40","a41","a42","a43") LOADW(PTR,2,3,"a44","a45","a46","a47") \
  LOADW(PTR,3,0,"a48","a49","a50","a51") LOADW(PTR,3,1,"a52","a53","a54","a55") \
  LOADW(PTR,3,2,"a56","a57","a58","a59") LOADW(PTR,3,3,"a60","a61","a62","a63") \
  asm volatile("s_nop 7");

#define MFMA1(ACC, RNG, BF) \
  asm("v_mfma_f32_16x16x32_bf16 %0, " RNG ", %1, %0" : "+v"(ACC) : "v"(BF))

// 16 MFMAs: acc[q] over kf, A = AGPR-resident weights. Hazard fences included.
#define MFMA_STEP(acc, bfr) do { \
  __builtin_amdgcn_sched_barrier(0); \
  asm volatile("s_nop 3" ::: AGCLOB);            /* VALU(init)->MFMA SrcC */ \
  __builtin_amdgcn_sched_barrier(0); \
  MFMA1(acc[0], "a[0:3]",   bfr[0]); MFMA1(acc[1], "a[16:19]", bfr[0]); \
  MFMA1(acc[2], "a[32:35]", bfr[0]); MFMA1(acc[3], "a[48:51]", bfr[0]); \
  MFMA1(acc[0], "a[4:7]",   bfr[1]); MFMA1(acc[1], "a[20:23]", bfr[1]); \
  MFMA1(acc[2], "a[36:39]", bfr[1]); MFMA1(acc[3], "a[52:55]", bfr[1]); \
  MFMA1(acc[0], "a[8:11]",  bfr[2]); MFMA1(acc[1], "a[24:27]", bfr[2]); \
  MFMA1(acc[2], "a[40:43]", bfr[2]); MFMA1(acc[3], "a[56:59]", bfr[2]); \
  MFMA1(acc[0], "a[12:15]", bfr[3]); MFMA1(acc[1], "a[28:31]", bfr[3]); \
  MFMA1(acc[2], "a[44:47]", bfr[3]); MFMA1(acc[3], "a[60:63]", bfr[3]); \
  __builtin_amdgcn_sched_barrier(0); \
  asm volatile("s_nop 7\n\ts_nop 7" ::: AGCLOB); /* MFMA D -> VALU read */ \
  __builtin_amdgcn_sched_barrier(0); \
} while (0)

// ---------------- prep: pack weights (prescaled by log2e) into MFMA frag order ----
// frag layout (A and B identical): tile=j>>4, kf=k>>5,
//   lane=(j&15)+16*((k&31)>>3), elem=k&7.
__global__ __launch_bounds__(256) void k_prep(
    const float* tseq, const float* init_in,
    const float* Wih0, const float* Whh0, const float* bih0, const float* bhh0,
    const float* Wih1, const float* Whh1, const float* bih1, const float* bhh1,
    const float* projW, const float* hW1,
    float* xs, u16* W0p, u16* W1ip, u16* W1hp, u16* projWp, u16* hW1p,
    float* bias0, float* bias1, float* wv0)
{
  int tid = blockIdx.x * blockDim.x + threadIdx.x;
  int stride = gridDim.x * blockDim.x;
  for (int i = tid; i < TT*BB; i += stride){
    int t = i / BB, b = i % BB;
    xs[i] = (t == 0) ? init_in[0] : tseq[b*TT + (t-1)];
  }
  for (int i = tid; i < 2*512*128; i += stride){
    int d = i / (512*128), r = i % (512*128);
    int j = r / 128, k = r % 128;
    float sc = ((j >> 7) == 2) ? L2E2 : L2E;
    int dst = ((((d*32 + (j>>4))*4 + (k>>5))*64) + ((j&15) + 16*((k&31)>>3)))*8 + (k&7);
    W0p[dst]  = f2bf(Whh0[i] * sc);
    W1hp[dst] = f2bf(Whh1[i] * sc);
  }
  for (int i = tid; i < 2*512*256; i += stride){
    int d = i / (512*256), r = i % (512*256);
    int j = r / 256, k = r % 256;
    float sc = ((j >> 7) == 2) ? L2E2 : L2E;
    int dst = ((((d*32 + (j>>4))*8 + (k>>5))*64) + ((j&15) + 16*((k&31)>>3)))*8 + (k&7);
    W1ip[dst] = f2bf(Wih1[i] * sc);
  }
  for (int i = tid; i < 128*256; i += stride){
    int j = i / 256, k = i % 256;
    int dst = ((((j>>4)*8 + (k>>5))*64) + ((j&15) + 16*((k&31)>>3)))*8 + (k&7);
    projWp[dst] = f2bf(projW[i]);
  }
  for (int i = tid; i < 128*128; i += stride){
    int j = i / 128, k = i % 128;
    int dst = ((((j>>4)*4 + (k>>5))*64) + ((j&15) + 16*((k&31)>>3)))*8 + (k&7);
    hW1p[dst] = f2bf(hW1[i]);
  }
  for (int i = tid; i < 2*512; i += stride){
    float sc = (((i & 511) >> 7) == 2) ? L2E2 : L2E;
    bias0[i] = (bih0[i] + bhh0[i]) * sc;
    bias1[i] = (bih1[i] + bhh1[i]) * sc;
    wv0[i]   = Wih0[i] * sc;
  }
}

// ---------------- encoder ---------------------------------------------------------
__global__ __launch_bounds__(256) void k_enc(
    const float* phys, const float* W1, const float* b1, const float* g1, const float* be1,
    const float* W2, const float* b2, const float* g2, const float* be2, float* h0enc)
{
  __shared__ float eL[8][256];
  int tid = threadIdx.x;
  int rr = tid >> 5, sub = tid & 31;
  int r = blockIdx.x * 8 + rr;
  float x[16];
#pragma unroll
  for (int k = 0; k < 16; ++k) x[k] = phys[r*16 + k];
  float y[8];
#pragma unroll
  for (int jj = 0; jj < 8; ++jj){
    int j = sub*8 + jj;
    float s = b1[j];
#pragma unroll
    for (int k = 0; k < 16; ++k) s += x[k] * W1[j*16 + k];
    y[jj] = s;
  }
  float sum = 0.f, sq = 0.f;
#pragma unroll
  for (int jj = 0; jj < 8; ++jj){ sum += y[jj]; sq += y[jj]*y[jj]; }
#pragma unroll
  for (int m = 16; m >= 1; m >>= 1){ sum += __shfl_xor(sum, m, 32); sq += __shfl_xor(sq, m, 32); }
  float mu = sum / 256.f;
  float rs = rsqrtf(sq / 256.f - mu*mu + 1e-5f);
#pragma unroll
  for (int jj = 0; jj < 8; ++jj){
    int j = sub*8 + jj;
    eL[rr][j] = fmaxf((y[jj] - mu) * rs * g1[j] + be1[j], 0.f);
  }
  __syncthreads();
  float y2[4];
#pragma unroll
  for (int jj = 0; jj < 4; ++jj){
    int j2 = sub*4 + jj;
    float s = b2[j2];
    const float* wrow = W2 + j2*256;
    for (int k = 0; k < 256; k += 4)
      s += eL[rr][k]*wrow[k] + eL[rr][k+1]*wrow[k+1] + eL[rr][k+2]*wrow[k+2] + eL[rr][k+3]*wrow[k+3];
    y2[jj] = s;
  }
  sum = 0.f; sq = 0.f;
#pragma unroll
  for (int jj = 0; jj < 4; ++jj){ sum += y2[jj]; sq += y2[jj]*y2[jj]; }
#pragma unroll
  for (int m = 16; m >= 1; m >>= 1){ sum += __shfl_xor(sum, m, 32); sq += __shfl_xor(sq, m, 32); }
  mu = sum / 128.f;
  rs = rsqrtf(sq / 128.f - mu*mu + 1e-5f);
#pragma unroll
  for (int jj = 0; jj < 4; ++jj){
    int j2 = sub*4 + jj;
    h0enc[r*128 + j2] = tanh_f((y2[jj]-mu)*rs*g2[j2] + be2[j2]);
  }
}

// ---------------- layer0 recurrence: weights AGPR-resident ------------------------
__global__ __launch_bounds__(512)
__attribute__((amdgpu_waves_per_eu(2, 2)))
void k_l0(
    const u16* __restrict__ W0p, const float* __restrict__ bias0,
    const float* __restrict__ wv0, const float* __restrict__ xs,
    const float* __restrict__ h0enc, u16* __restrict__ o0pack)
{
  __shared__ __align__(16) u16 Xb[2][4][512];
  __shared__ __align__(16) float xl[TT*16];
  int bx = blockIdx.x;
  int tile = bx & 31, d = bx >> 5;
  int tid = threadIdx.x, w = tid >> 6, l = tid & 63;
  int r0 = tile * 16, lrow = l & 15, lk = l >> 4;

  for (int i = tid; i < TT*16; i += 512){
    int t = i >> 4, r = i & 15;
    xl[i] = xs[t*BB + r0 + r];
  }
  if (tid < 256){
    int kf = tid >> 6, ll = tid & 63;
    const float* src = h0enc + (r0 + (ll & 15))*128 + kf*32 + 8*(ll >> 4);
    u16* dstp = &Xb[0][kf][ll*8];
#pragma unroll
    for (int i = 0; i < 8; ++i) dstp[i] = f2bf(src[i]);
  }

  const u16* Wb = W0p + (size_t)d*32*4*512;
  LOADW_ALL(Wb)

  float bias[4][4], wv[4][4];
#pragma unroll
  for (int q = 0; q < 4; ++q){
    int tq = w + 8*q;
#pragma unroll
    for (int jj = 0; jj < 4; ++jj){
      int j = tq*16 + 4*lk + jj;
      bias[q][jj] = bias0[d*512 + j];
      wv[q][jj]   = wv0[d*512 + j];
    }
  }
  float c[4] = {0.f,0.f,0.f,0.f};
  int jout = w*16 + 4*lk;
  int kfx = jout >> 5;
  int sl  = lrow + 16*((jout & 31) >> 3);
  int eb  = jout & 7;
  int kfo = 4*d + kfx;
  __syncthreads();

#pragma unroll 2
  for (int t = 0; t < TT; ++t){
    int cur = t & 1, nxt = cur ^ 1;
    v8s bfr[4];
#pragma unroll
    for (int kf = 0; kf < 4; ++kf) bfr[kf] = *(const v8s*)&Xb[cur][kf][l*8];
    float xv = xl[t*16 + lrow];
    f32x4 acc[4];
#pragma unroll
    for (int q = 0; q < 4; ++q)
#pragma unroll
      for (int jj = 0; jj < 4; ++jj)
        acc[q][jj] = fmaf(xv, wv[q][jj], bias[q][jj]);
    MFMA_STEP(acc, bfr);
    f32x4 hv;
#pragma unroll
    for (int jj = 0; jj < 4; ++jj){
      float si = sigm2(acc[0][jj]);
      float sf = sigm2(acc[1][jj]);
      float tg = tanh2(acc[2][jj]);
      float so = sigm2(acc[3][jj]);
      float cn = fmaf(sf, c[jj], si*tg);
      c[jj] = cn;
      float s2 = sigm2(L2E2 * cn);
      hv[jj] = so * fmaf(2.f, s2, -1.f);
    }
    uint2 hp = pack4(hv);
    *(uint2*)&Xb[nxt][kfx][sl*8 + eb] = hp;
    size_t off = ((((size_t)t*32 + tile)*8 + kfo)*64 + sl)*8 + eb;
    *(uint2*)&o0pack[off] = hp;     // fire-and-forget
    bar_lds();
  }
}

// ---------------- Z1 = bias1 + o0 @ Wih1^T (parallel GEMM, bf16 out) --------------
__global__ __launch_bounds__(256) void k_zgemm(
    const u16* W1ip, const float* bias1p, const u16* o0pack, u16* z1p)
{
  int bx = blockIdx.x;
  int nc = bx & 3, bg = (bx >> 2) & 7, t = bx >> 5;
  int w = threadIdx.x >> 6, l = threadIdx.x & 63;
  int btile = bg*4 + w;
  int lk4 = (l >> 4) * 4;
  v8s bfrag[8];
#pragma unroll
  for (int kf = 0; kf < 8; ++kf)
    bfrag[kf] = *(const v8s*)&o0pack[((((size_t)t*32 + btile)*8 + kf)*64 + l)*8];
  f32x4 acc[16];
#pragma unroll
  for (int nt = 0; nt < 16; ++nt){
    int ntg = nc*16 + nt;
    acc[nt] = *(const f32x4*)&bias1p[(ntg >> 5)*512 + (ntg & 31)*16 + lk4];
  }
#pragma unroll
  for (int kf = 0; kf < 8; ++kf){
#pragma unroll
    for (int nt = 0; nt < 16; ++nt){
      int ntg = nc*16 + nt;
      int dir = ntg >> 5, tl = ntg & 31;
      v8s a = *(const v8s*)&W1ip[((((size_t)dir*32 + tl)*8 + kf)*64 + l)*8];
      acc[nt] = __builtin_amdgcn_mfma_f32_16x16x32_bf16(a, bfrag[kf], acc[nt], 0, 0, 0);
    }
  }
#pragma unroll
  for (int nt = 0; nt < 16; ++nt){
    int ntg = nc*16 + nt;
    uint2 zp = pack4(acc[nt]);
    *(uint2*)&z1p[((((size_t)t*32 + btile)*64 + ntg)*64 + l)*4] = zp;
  }
}

// ---------------- layer1 recurrence: weights AGPR-resident, depth-2 Z prefetch ----
__global__ __launch_bounds__(512)
__attribute__((amdgpu_waves_per_eu(2, 2)))
void k_l1(
    const u16* __restrict__ W1hp, const u16* __restrict__ z1p,
    const float* __restrict__ h0enc, u16* __restrict__ h1b)
{
  __shared__ __align__(16) u16 Xh[2][4][512];
  int bx = blockIdx.x;
  int tile = bx & 31, d = bx >> 5;
  int tid = threadIdx.x, w = tid >> 6, l = tid & 63;
  int r0 = tile * 16, lrow = l & 15, lk = l >> 4;

  if (tid < 256){
    int kf = tid >> 6, ll = tid & 63;
    const float* src = h0enc + (r0 + (ll & 15))*128 + kf*32 + 8*(ll >> 4);
    u16* dstp = &Xh[0][kf][ll*8];
#pragma unroll
    for (int i = 0; i < 8; ++i) dstp[i] = f2bf(src[i]);
  }

  const u16* Wh = W1hp + (size_t)d*32*4*512;
  LOADW_ALL(Wh)

  float c[4] = {0.f,0.f,0.f,0.f};
  int jout = w*16 + 4*lk;
  int kfx = jout >> 5;
  int sl  = lrow + 16*((jout & 31) >> 3);
  int eb  = jout & 7;
  int zcol = d*32 + w;    // base ntg for q=0

  uint2 zr[4], zn[4];
#pragma unroll
  for (int q = 0; q < 4; ++q)
    zr[q] = *(const uint2*)&z1p[(((size_t)tile*64 + zcol + 8*q)*64 + l)*4];
#pragma unroll
  for (int q = 0; q < 4; ++q)
    zn[q] = *(const uint2*)&z1p[((((size_t)1*32 + tile)*64 + zcol + 8*q)*64 + l)*4];
  __syncthreads();

#pragma unroll 2
  for (int t = 0; t < TT; ++t){
    int cur = t & 1, nxt = cur ^ 1;
    v8s bfr[4];
#pragma unroll
    for (int kf = 0; kf < 4; ++kf) bfr[kf] = *(const v8s*)&Xh[cur][kf][l*8];
    f32x4 acc[4];
#pragma unroll
    for (int q = 0; q < 4; ++q){
      acc[q][0] = lo_bits(zr[q].x);
      acc[q][1] = hi_bits(zr[q].x);
      acc[q][2] = lo_bits(zr[q].y);
      acc[q][3] = hi_bits(zr[q].y);
    }
    MFMA_STEP(acc, bfr);
    f32x4 hv;
#pragma unroll
    for (int jj = 0; jj < 4; ++jj){
      float si = sigm2(acc[0][jj]);
      float sf = sigm2(acc[1][jj]);
      float tg = tanh2(acc[2][jj]);
      float so = sigm2(acc[3][jj]);
      float cn = fmaf(sf, c[jj], si*tg);
      c[jj] = cn;
      float s2 = sigm2(L2E2 * cn);
      hv[jj] = so * fmaf(2.f, s2, -1.f);
    }
    uint2 hp = pack4(hv);
    *(uint2*)&Xh[nxt][kfx][sl*8 + eb] = hp;
    int hidx = ((t*BB + r0 + lrow) << 8) + (d << 7) + jout;
    *(uint2*)&h1b[hidx] = hp;       // fire-and-forget
    // rotate prefetch regs and issue t+2
#pragma unroll
    for (int q = 0; q < 4; ++q) zr[q] = zn[q];
    int tp = (t + 2 < TT) ? t + 2 : TT - 1;
#pragma unroll
    for (int q = 0; q < 4; ++q)
      zn[q] = *(const uint2*)&z1p[((((size_t)tp*32 + tile)*64 + zcol + 8*q)*64 + l)*4];
    bar_lds();
  }
}

// ---------------- head: LN -> proj -> relu head1 -> head2 via MFMA ---------------
__global__ __launch_bounds__(256) void k_head(
    const u16* h1b, const float* lng, const float* lnb,
    const u16* projWp, const float* projb,
    const u16* hW1p, const float* hb1, const float* hW2, const float* hb2,
    float* qout)
{
  __shared__ __align__(16) u16 xls[4][16*256];  // 32 KB, swizzled
  __shared__ __align__(16) u16 pls[4][16*128];  // 16 KB, swizzled
  int w = threadIdx.x >> 6, l = threadIdx.x & 63;
  size_t g0 = (size_t)blockIdx.x*64 + w*16;
  int row = l >> 2, qc = l & 3;

  const u16* srcb = h1b + (g0 + row)*256;
  f32x4 v[16];
#pragma unroll
  for (int m = 0; m < 16; ++m){
    uint2 p = *(const uint2*)&srcb[m*16 + qc*4];
    v[m][0] = lo_bits(p.x);
    v[m][1] = hi_bits(p.x);
    v[m][2] = lo_bits(p.y);
    v[m][3] = hi_bits(p.y);
  }
  float sum = 0.f, sq = 0.f;
#pragma unroll
  for (int m = 0; m < 16; ++m){
#pragma unroll
    for (int i = 0; i < 4; ++i){ sum += v[m][i]; sq += v[m][i]*v[m][i]; }
  }
  sum += __shfl_xor(sum, 1); sq += __shfl_xor(sq, 1);
  sum += __shfl_xor(sum, 2); sq += __shfl_xor(sq, 2);
  float mu = sum / 256.f;
  float rs = rsqrtf(sq / 256.f - mu*mu + 1e-5f);
  u16* xw = xls[w];
  int rsw = (row & 7) << 3;    // 16B-granule XOR swizzle, u16 units
#pragma unroll
  for (int m = 0; m < 16; ++m){
    int cb = m*16 + qc*4;
    f32x4 gq = *(const f32x4*)&lng[cb];
    f32x4 bq = *(const f32x4*)&lnb[cb];
    f32x4 xn;
#pragma unroll
    for (int i = 0; i < 4; ++i) xn[i] = (v[m][i]-mu)*rs*gq[i] + bq[i];
    *(uint2*)&xw[(row*256 + cb) ^ rsw] = pack4(xn);
  }

  // proj: (16x256)@(256x128) MFMA
  int lk = l >> 4, r = l & 15;
  int rsw2 = (r & 7) << 3;
  f32x4 acc[8];
#pragma unroll
  for (int nt = 0; nt < 8; ++nt) acc[nt] = *(const f32x4*)&projb[nt*16 + lk*4];
#pragma unroll
  for (int kf = 0; kf < 8; ++kf){
    v8s b = *(const v8s*)&xw[(r*256 + kf*32 + lk*8) ^ rsw2];
#pragma unroll
    for (int nt = 0; nt < 8; ++nt){
      v8s a = *(const v8s*)&projWp[(((size_t)nt*8 + kf)*64 + l)*8];
      acc[nt] = __builtin_amdgcn_mfma_f32_16x16x32_bf16(a, b, acc[nt], 0, 0, 0);
    }
  }
  u16* pw = pls[w];
#pragma unroll
  for (int nt = 0; nt < 8; ++nt)
    *(uint2*)&pw[(r*128 + nt*16 + lk*4) ^ rsw2] = pack4(acc[nt]);

  // head1: (16x128)@(128x128) MFMA
  f32x4 acc2[8];
#pragma unroll
  for (int nt = 0; nt < 8; ++nt) acc2[nt] = *(const f32x4*)&hb1[nt*16 + lk*4];
#pragma unroll
  for (int kf = 0; kf < 4; ++kf){
    v8s b = *(const v8s*)&pw[(r*128 + kf*32 + lk*8) ^ rsw2];
#pragma unroll
    for (int nt = 0; nt < 8; ++nt){
      v8s a = *(const v8s*)&hW1p[(((size_t)nt*4 + kf)*64 + l)*8];
      acc2[nt] = __builtin_amdgcn_mfma_f32_16x16x32_bf16(a, b, acc2[nt], 0, 0, 0);
    }
  }
  // head2: relu + dot with hW2, reduce lanes sharing r
  float part = 0.f;
#pragma unroll
  for (int nt = 0; nt < 8; ++nt){
    f32x4 w2 = *(const f32x4*)&hW2[nt*16 + lk*4];
#pragma unroll
    for (int jj = 0; jj < 4; ++jj) part += fmaxf(acc2[nt][jj], 0.f) * w2[jj];
  }
  part += __shfl_xor(part, 16);
  part += __shfl_xor(part, 32);
  if (l < 16) qout[g0 + l] = part + hb2[0];
}

// ---------------- AR blend --------------------------------------------------------
__global__ __launch_bounds__(512) void k_blend(const float* qout, float* out)
{
  int b = threadIdx.x;
  float pred = 0.f;
  for (int t0 = 0; t0 < TT; t0 += 16){
    float v[16];
#pragma unroll
    for (int i = 0; i < 16; ++i) v[i] = qout[(t0+i)*BB + b];
#pragma unroll
    for (int i = 0; i < 16; ++i){
      pred = (t0 + i == 0) ? v[i] : 0.8f*v[i] + 0.2f*pred;
      out[b*TT + t0 + i] = pred;
    }
  }
}

extern "C" void kernel_launch(void* const* d_in, const int* in_sizes, int n_in,
                              void* d_out, int out_size, void* d_ws, size_t ws_size,
                              hipStream_t stream) {
  const float* physical   = (const float*)d_in[0];
  const float* target_seq = (const float*)d_in[1];
  const float* enc_W1     = (const float*)d_in[2];
  const float* enc_b1     = (const float*)d_in[3];
  const float* enc_ln1_g  = (const float*)d_in[4];
  const float* enc_ln1_b  = (const float*)d_in[5];
  const float* enc_W2     = (const float*)d_in[6];
  const float* enc_b2     = (const float*)d_in[7];
  const float* enc_ln2_g  = (const float*)d_in[8];
  const float* enc_ln2_b  = (const float*)d_in[9];
  const float* Wih0       = (const float*)d_in[10];
  const float* Whh0       = (const float*)d_in[11];
  const float* bih0       = (const float*)d_in[12];
  const float* bhh0       = (const float*)d_in[13];
  const float* Wih1       = (const float*)d_in[14];
  const float* Whh1       = (const float*)d_in[15];
  const float* bih1       = (const float*)d_in[16];
  const float* bhh1       = (const float*)d_in[17];
  const float* ln_g       = (const float*)d_in[18];
  const float* ln_b       = (const float*)d_in[19];
  const float* proj_W     = (const float*)d_in[20];
  const float* proj_b     = (const float*)d_in[21];
  const float* head_W1    = (const float*)d_in[22];
  const float* head_b1    = (const float*)d_in[23];
  const float* head_W2    = (const float*)d_in[24];
  const float* head_b2    = (const float*)d_in[25];
  const float* init_input = (const float*)d_in[26];

  size_t off = 0;
  char* base = (char*)d_ws;
  auto carve = [&](size_t bytes) -> void* {
    void* p = base + off;
    off += (bytes + 255) & ~(size_t)255;
    return p;
  };
  u16*   o0pack  = (u16*)  carve((size_t)TT*32*8*64*8*2);     // 32 MB bf16 frag-packed
  u16*   h1b     = (u16*)  carve((size_t)TT*BB*256*2);        // 32 MB bf16
  u16*   z1p     = (u16*)  carve((size_t)TT*32*64*64*4*2);    // 128 MB bf16 C-frag
  float* qout    = (float*)carve((size_t)TT*BB*4);
  float* h0enc   = (float*)carve((size_t)BB*128*4);
  float* xs      = (float*)carve((size_t)TT*BB*4);
  u16*   W0p     = (u16*)  carve((size_t)2*512*128*2);
  u16*   W1ip    = (u16*)  carve((size_t)2*512*256*2);
  u16*   W1hp    = (u16*)  carve((size_t)2*512*128*2);
  u16*   projWp  = (u16*)  carve((size_t)128*256*2);
  u16*   hW1p    = (u16*)  carve((size_t)128*128*2);
  float* bias0   = (float*)carve(4096);
  float* bias1   = (float*)carve(4096);
  float* wv0     = (float*)carve(4096);

  k_prep<<<256, 256, 0, stream>>>(target_seq, init_input, Wih0, Whh0, bih0, bhh0,
                                  Wih1, Whh1, bih1, bhh1, proj_W, head_W1,
                                  xs, W0p, W1ip, W1hp, projWp, hW1p,
                                  bias0, bias1, wv0);
  k_enc<<<64, 256, 0, stream>>>(physical, enc_W1, enc_b1, enc_ln1_g, enc_ln1_b,
                                enc_W2, enc_b2, enc_ln2_g, enc_ln2_b, h0enc);
  k_l0<<<64, 512, 0, stream>>>(W0p, bias0, wv0, xs, h0enc, o0pack);
  k_zgemm<<<4096, 256, 0, stream>>>(W1ip, bias1, o0pack, z1p);
  k_l1<<<64, 512, 0, stream>>>(W1hp, z1p, h0enc, h1b);
  k_head<<<1024, 256, 0, stream>>>(h1b, ln_g, ln_b, projWp, proj_b,
                                   hW1p, head_b1, head_W2, head_b2, qout);
  k_blend<<<1, 512, 0, stream>>>(qout, (float*)d_out);
}

// Round 8
// 368.052 us; speedup vs baseline: 1.0861x; 1.0861x over previous
//
#include <hip/hip_runtime.h>
#include <hip/hip_bf16.h>

#define BB 512
#define TT 128

typedef unsigned short u16;
typedef short v8s __attribute__((ext_vector_type(8)));
typedef float f32x4 __attribute__((ext_vector_type(4)));

#define L2E  1.4426950408889634f
#define L2E2 2.8853900817779268f

__device__ __forceinline__ u16 f2bf(float x){
  union { float f; unsigned int u; } v; v.f = x;
  unsigned int r = (v.u + 0x7fffu + ((v.u >> 16) & 1u)) >> 16;
  return (u16)r;
}
__device__ __forceinline__ float lo_bits(unsigned u){
  union { unsigned int i; float f; } v; v.i = u << 16; return v.f;
}
__device__ __forceinline__ float hi_bits(unsigned u){
  union { unsigned int i; float f; } v; v.i = u & 0xffff0000u; return v.f;
}
// fast bf16 pack: RNE, matches f2bf
__device__ __forceinline__ uint2 pack4(f32x4 a){
  uint2 r;
  asm("v_cvt_pk_bf16_f32 %0, %1, %2" : "=v"(r.x) : "v"(a[0]), "v"(a[1]));
  asm("v_cvt_pk_bf16_f32 %0, %1, %2" : "=v"(r.y) : "v"(a[2]), "v"(a[3]));
  return r;
}
__device__ __forceinline__ float rcp_f(float x){ return __builtin_amdgcn_rcpf(x); }
__device__ __forceinline__ float exp2_f(float x){
  float r; asm("v_exp_f32 %0, %1" : "=v"(r) : "v"(x)); return r;
}
// inputs prescaled by log2e (i,f,o) and 2*log2e (g)
__device__ __forceinline__ float sigm2(float y){ return rcp_f(1.f + exp2_f(-y)); }
__device__ __forceinline__ float tanh2(float y){ return fmaf(2.f, sigm2(y), -1.f); }

// encoder-only (unscaled) helpers
__device__ __forceinline__ float tanh_f(float x){
  float e = __expf(-2.f * fabsf(x));
  float r = (1.f - e) * rcp_f(1.f + e);
  return copysignf(r, x);
}
// barrier that waits only LDS ops: global stores/loads stay in flight
__device__ __forceinline__ void bar_lds(){
  __builtin_amdgcn_sched_barrier(0);
  asm volatile("s_waitcnt lgkmcnt(0)" ::: "memory");
  __builtin_amdgcn_s_barrier();
  __builtin_amdgcn_sched_barrier(0);
}

// ---------------- prep: pack weights (prescaled by log2e) into MFMA frag order ----
// frag layout (A and B identical): tile=j>>4, kf=k>>5,
//   lane=(j&15)+16*((k&31)>>3), elem=k&7.
__global__ __launch_bounds__(256) void k_prep(
    const float* tseq, const float* init_in,
    const float* Wih0, const float* Whh0, const float* bih0, const float* bhh0,
    const float* Wih1, const float* Whh1, const float* bih1, const float* bhh1,
    const float* projW, const float* hW1,
    float* xs, u16* W0p, u16* W1ip, u16* W1hp, u16* projWp, u16* hW1p,
    float* bias0, float* bias1, float* wv0)
{
  int tid = blockIdx.x * blockDim.x + threadIdx.x;
  int stride = gridDim.x * blockDim.x;
  for (int i = tid; i < TT*BB; i += stride){
    int t = i / BB, b = i % BB;
    xs[i] = (t == 0) ? init_in[0] : tseq[b*TT + (t-1)];
  }
  for (int i = tid; i < 2*512*128; i += stride){
    int d = i / (512*128), r = i % (512*128);
    int j = r / 128, k = r % 128;
    float sc = ((j >> 7) == 2) ? L2E2 : L2E;
    int dst = ((((d*32 + (j>>4))*4 + (k>>5))*64) + ((j&15) + 16*((k&31)>>3)))*8 + (k&7);
    W0p[dst]  = f2bf(Whh0[i] * sc);
    W1hp[dst] = f2bf(Whh1[i] * sc);
  }
  for (int i = tid; i < 2*512*256; i += stride){
    int d = i / (512*256), r = i % (512*256);
    int j = r / 256, k = r % 256;
    float sc = ((j >> 7) == 2) ? L2E2 : L2E;
    int dst = ((((d*32 + (j>>4))*8 + (k>>5))*64) + ((j&15) + 16*((k&31)>>3)))*8 + (k&7);
    W1ip[dst] = f2bf(Wih1[i] * sc);
  }
  for (int i = tid; i < 128*256; i += stride){
    int j = i / 256, k = i % 256;
    int dst = ((((j>>4)*8 + (k>>5))*64) + ((j&15) + 16*((k&31)>>3)))*8 + (k&7);
    projWp[dst] = f2bf(projW[i]);
  }
  for (int i = tid; i < 128*128; i += stride){
    int j = i / 128, k = i % 128;
    int dst = ((((j>>4)*4 + (k>>5))*64) + ((j&15) + 16*((k&31)>>3)))*8 + (k&7);
    hW1p[dst] = f2bf(hW1[i]);
  }
  for (int i = tid; i < 2*512; i += stride){
    float sc = (((i & 511) >> 7) == 2) ? L2E2 : L2E;
    bias0[i] = (bih0[i] + bhh0[i]) * sc;
    bias1[i] = (bih1[i] + bhh1[i]) * sc;
    wv0[i]   = Wih0[i] * sc;
  }
}

// ---------------- encoder ---------------------------------------------------------
__global__ __launch_bounds__(256) void k_enc(
    const float* phys, const float* W1, const float* b1, const float* g1, const float* be1,
    const float* W2, const float* b2, const float* g2, const float* be2, float* h0enc)
{
  __shared__ float eL[8][256];
  int tid = threadIdx.x;
  int rr = tid >> 5, sub = tid & 31;
  int r = blockIdx.x * 8 + rr;
  float x[16];
#pragma unroll
  for (int k = 0; k < 16; ++k) x[k] = phys[r*16 + k];
  float y[8];
#pragma unroll
  for (int jj = 0; jj < 8; ++jj){
    int j = sub*8 + jj;
    float s = b1[j];
#pragma unroll
    for (int k = 0; k < 16; ++k) s += x[k] * W1[j*16 + k];
    y[jj] = s;
  }
  float sum = 0.f, sq = 0.f;
#pragma unroll
  for (int jj = 0; jj < 8; ++jj){ sum += y[jj]; sq += y[jj]*y[jj]; }
#pragma unroll
  for (int m = 16; m >= 1; m >>= 1){ sum += __shfl_xor(sum, m, 32); sq += __shfl_xor(sq, m, 32); }
  float mu = sum / 256.f;
  float rs = rsqrtf(sq / 256.f - mu*mu + 1e-5f);
#pragma unroll
  for (int jj = 0; jj < 8; ++jj){
    int j = sub*8 + jj;
    eL[rr][j] = fmaxf((y[jj] - mu) * rs * g1[j] + be1[j], 0.f);
  }
  __syncthreads();
  float y2[4];
#pragma unroll
  for (int jj = 0; jj < 4; ++jj){
    int j2 = sub*4 + jj;
    float s = b2[j2];
    const float* wrow = W2 + j2*256;
    for (int k = 0; k < 256; k += 4)
      s += eL[rr][k]*wrow[k] + eL[rr][k+1]*wrow[k+1] + eL[rr][k+2]*wrow[k+2] + eL[rr][k+3]*wrow[k+3];
    y2[jj] = s;
  }
  sum = 0.f; sq = 0.f;
#pragma unroll
  for (int jj = 0; jj < 4; ++jj){ sum += y2[jj]; sq += y2[jj]*y2[jj]; }
#pragma unroll
  for (int m = 16; m >= 1; m >>= 1){ sum += __shfl_xor(sum, m, 32); sq += __shfl_xor(sq, m, 32); }
  mu = sum / 128.f;
  rs = rsqrtf(sq / 128.f - mu*mu + 1e-5f);
#pragma unroll
  for (int jj = 0; jj < 4; ++jj){
    int j2 = sub*4 + jj;
    h0enc[r*128 + j2] = tanh_f((y2[jj]-mu)*rs*g2[j2] + be2[j2]);
  }
}

// ---------------- layer0 recurrence (round-4 config: issue-bound, compiler-sched) -
__global__ __launch_bounds__(512) void k_l0(
    const u16* W0p, const float* bias0, const float* wv0, const float* xs,
    const float* h0enc, u16* o0pack)
{
  __shared__ __align__(16) u16 Xb[2][4][512];
  __shared__ __align__(16) float xl[TT*16];
  int bx = blockIdx.x;
  int tile = bx & 31, d = bx >> 5;
  int tid = threadIdx.x, w = tid >> 6, l = tid & 63;
  int r0 = tile * 16, lrow = l & 15, lk = l >> 4;

  for (int i = tid; i < TT*16; i += 512){
    int t = i >> 4, r = i & 15;
    xl[i] = xs[t*BB + r0 + r];
  }
  if (tid < 256){
    int kf = tid >> 6, ll = tid & 63;
    const float* src = h0enc + (r0 + (ll & 15))*128 + kf*32 + 8*(ll >> 4);
    u16* dstp = &Xb[0][kf][ll*8];
#pragma unroll
    for (int i = 0; i < 8; ++i) dstp[i] = f2bf(src[i]);
  }

  const u16* Wb = W0p + (size_t)d*32*4*512;
  v8s wa[4][4];
#pragma unroll
  for (int q = 0; q < 4; ++q)
#pragma unroll
    for (int kf = 0; kf < 4; ++kf)
      wa[q][kf] = *(const v8s*)(Wb + (size_t)(((w + 8*q)*4 + kf)*64 + l)*8);

  float bias[4][4], wv[4][4];
#pragma unroll
  for (int q = 0; q < 4; ++q){
    int tq = w + 8*q;
#pragma unroll
    for (int jj = 0; jj < 4; ++jj){
      int j = tq*16 + 4*lk + jj;
      bias[q][jj] = bias0[d*512 + j];
      wv[q][jj]   = wv0[d*512 + j];
    }
  }
  float c[4] = {0.f,0.f,0.f,0.f};
  int jout = w*16 + 4*lk;
  int kfx = jout >> 5;
  int sl  = lrow + 16*((jout & 31) >> 3);
  int eb  = jout & 7;
  int kfo = 4*d + kfx;
  __syncthreads();

#pragma unroll 2
  for (int t = 0; t < TT; ++t){
    int cur = t & 1, nxt = cur ^ 1;
    v8s bfr[4];
#pragma unroll
    for (int kf = 0; kf < 4; ++kf) bfr[kf] = *(const v8s*)&Xb[cur][kf][l*8];
    float xv = xl[t*16 + lrow];
    f32x4 acc[4];
#pragma unroll
    for (int q = 0; q < 4; ++q)
#pragma unroll
      for (int jj = 0; jj < 4; ++jj)
        acc[q][jj] = fmaf(xv, wv[q][jj], bias[q][jj]);
#pragma unroll
    for (int kf = 0; kf < 4; ++kf)
#pragma unroll
      for (int q = 0; q < 4; ++q)
        acc[q] = __builtin_amdgcn_mfma_f32_16x16x32_bf16(wa[q][kf], bfr[kf], acc[q], 0, 0, 0);
    f32x4 hv;
#pragma unroll
    for (int jj = 0; jj < 4; ++jj){
      float si = sigm2(acc[0][jj]);
      float sf = sigm2(acc[1][jj]);
      float tg = tanh2(acc[2][jj]);
      float so = sigm2(acc[3][jj]);
      float cn = fmaf(sf, c[jj], si*tg);
      c[jj] = cn;
      float s2 = sigm2(L2E2 * cn);
      hv[jj] = so * fmaf(2.f, s2, -1.f);
    }
    uint2 hp = pack4(hv);
    *(uint2*)&Xb[nxt][kfx][sl*8 + eb] = hp;
    size_t off = ((((size_t)t*32 + tile)*8 + kfo)*64 + sl)*8 + eb;
    *(uint2*)&o0pack[off] = hp;     // fire-and-forget
    bar_lds();
  }
}

// ---------------- Z1 = bias1 + o0 @ Wih1^T, W staged via LDS (shared by 4 waves) --
// grid: t(128) x bg(8: 4-btile groups) x nc(8: 8-nt chunks) = 8192 blocks
__global__ __launch_bounds__(256) void k_zgemm(
    const u16* W1ip, const float* bias1p, const u16* o0pack, u16* z1p)
{
  __shared__ __align__(16) u16 Wl[8][4][64][8];   // 32 KB: [nt][kq][lane][e]
  int bx = blockIdx.x;
  int nc = bx & 7, bg = (bx >> 3) & 7, t = bx >> 6;
  int tid = threadIdx.x;
  int w = tid >> 6, l = tid & 63;
  int btile = bg*4 + w;
  int lk4 = (l >> 4) * 4;
  const u16* Wsrc = W1ip + (size_t)nc*8*8*64*8;   // nt-major contiguous chunk
  u16* WlF = &Wl[0][0][0][0];

  v8s bfrag[8];
#pragma unroll
  for (int kf = 0; kf < 8; ++kf)
    bfrag[kf] = *(const v8s*)&o0pack[((((size_t)t*32 + btile)*8 + kf)*64 + l)*8];
  f32x4 acc[8];
#pragma unroll
  for (int nt = 0; nt < 8; ++nt){
    int ntg = nc*8 + nt;
    acc[nt] = *(const f32x4*)&bias1p[(ntg >> 5)*512 + (ntg & 31)*16 + lk4];
  }
#pragma unroll
  for (int ph = 0; ph < 2; ++ph){
    if (ph) __syncthreads();          // protect buffer reuse
    // stage 32 KB: src (nt, kf=ph*4..ph*4+3, lane) -> Wl[nt][kq][lane]
#pragma unroll
    for (int i = 0; i < 8; ++i){
      int cid = i*256 + tid;          // coalesced 16B chunks
      int nt = cid >> 8, r = cid & 255;
      v8s v = *(const v8s*)&Wsrc[(size_t)(nt*8 + ph*4)*512 + r*8];
      *(v8s*)&WlF[cid*8] = v;
    }
    __syncthreads();
#pragma unroll
    for (int kq = 0; kq < 4; ++kq){
      int kf = ph*4 + kq;
#pragma unroll
      for (int nt = 0; nt < 8; ++nt){
        v8s a = *(const v8s*)&Wl[nt][kq][l][0];
        acc[nt] = __builtin_amdgcn_mfma_f32_16x16x32_bf16(a, bfrag[kf], acc[nt], 0, 0, 0);
      }
    }
  }
#pragma unroll
  for (int nt = 0; nt < 8; ++nt){
    int ntg = nc*8 + nt;
    uint2 zp = pack4(acc[nt]);
    *(uint2*)&z1p[((((size_t)t*32 + btile)*64 + ntg)*64 + l)*4] = zp;
  }
}

// ---------------- layer1 recurrence (round-4 config), depth-2 Z prefetch ----------
__global__ __launch_bounds__(512) void k_l1(
    const u16* W1hp, const u16* z1p, const float* h0enc, u16* h1b)
{
  __shared__ __align__(16) u16 Xh[2][4][512];
  int bx = blockIdx.x;
  int tile = bx & 31, d = bx >> 5;
  int tid = threadIdx.x, w = tid >> 6, l = tid & 63;
  int r0 = tile * 16, lrow = l & 15, lk = l >> 4;

  if (tid < 256){
    int kf = tid >> 6, ll = tid & 63;
    const float* src = h0enc + (r0 + (ll & 15))*128 + kf*32 + 8*(ll >> 4);
    u16* dstp = &Xh[0][kf][ll*8];
#pragma unroll
    for (int i = 0; i < 8; ++i) dstp[i] = f2bf(src[i]);
  }

  const u16* Wh = W1hp + (size_t)d*32*4*512;
  v8s wh[4][4];
#pragma unroll
  for (int q = 0; q < 4; ++q)
#pragma unroll
    for (int kf = 0; kf < 4; ++kf)
      wh[q][kf] = *(const v8s*)(Wh + (size_t)(((w + 8*q)*4 + kf)*64 + l)*8);

  float c[4] = {0.f,0.f,0.f,0.f};
  int jout = w*16 + 4*lk;
  int kfx = jout >> 5;
  int sl  = lrow + 16*((jout & 31) >> 3);
  int eb  = jout & 7;
  int zcol = d*32 + w;    // base ntg for q=0

  uint2 zr[4], zn[4];
#pragma unroll
  for (int q = 0; q < 4; ++q)
    zr[q] = *(const uint2*)&z1p[(((size_t)tile*64 + zcol + 8*q)*64 + l)*4];
#pragma unroll
  for (int q = 0; q < 4; ++q)
    zn[q] = *(const uint2*)&z1p[((((size_t)1*32 + tile)*64 + zcol + 8*q)*64 + l)*4];
  __syncthreads();

#pragma unroll 2
  for (int t = 0; t < TT; ++t){
    int cur = t & 1, nxt = cur ^ 1;
    v8s bh[4];
#pragma unroll
    for (int kf = 0; kf < 4; ++kf) bh[kf] = *(const v8s*)&Xh[cur][kf][l*8];
    f32x4 acc[4];
#pragma unroll
    for (int q = 0; q < 4; ++q){
      acc[q][0] = lo_bits(zr[q].x);
      acc[q][1] = hi_bits(zr[q].x);
      acc[q][2] = lo_bits(zr[q].y);
      acc[q][3] = hi_bits(zr[q].y);
    }
#pragma unroll
    for (int kf = 0; kf < 4; ++kf)
#pragma unroll
      for (int q = 0; q < 4; ++q)
        acc[q] = __builtin_amdgcn_mfma_f32_16x16x32_bf16(wh[q][kf], bh[kf], acc[q], 0, 0, 0);
    f32x4 hv;
#pragma unroll
    for (int jj = 0; jj < 4; ++jj){
      float si = sigm2(acc[0][jj]);
      float sf = sigm2(acc[1][jj]);
      float tg = tanh2(acc[2][jj]);
      float so = sigm2(acc[3][jj]);
      float cn = fmaf(sf, c[jj], si*tg);
      c[jj] = cn;
      float s2 = sigm2(L2E2 * cn);
      hv[jj] = so * fmaf(2.f, s2, -1.f);
    }
    uint2 hp = pack4(hv);
    *(uint2*)&Xh[nxt][kfx][sl*8 + eb] = hp;
    int hidx = ((t*BB + r0 + lrow) << 8) + (d << 7) + jout;
    *(uint2*)&h1b[hidx] = hp;       // fire-and-forget
    // rotate prefetch regs and issue t+2
#pragma unroll
    for (int q = 0; q < 4; ++q) zr[q] = zn[q];
    int tp = (t + 2 < TT) ? t + 2 : TT - 1;
#pragma unroll
    for (int q = 0; q < 4; ++q)
      zn[q] = *(const uint2*)&z1p[((((size_t)tp*32 + tile)*64 + zcol + 8*q)*64 + l)*4];
    bar_lds();
  }
}

// ---------------- head: LN -> proj -> relu head1 -> head2 via MFMA ---------------
__global__ __launch_bounds__(256) void k_head(
    const u16* h1b, const float* lng, const float* lnb,
    const u16* projWp, const float* projb,
    const u16* hW1p, const float* hb1, const float* hW2, const float* hb2,
    float* qout)
{
  __shared__ __align__(16) u16 xls[4][16*256];  // 32 KB, swizzled
  __shared__ __align__(16) u16 pls[4][16*128];  // 16 KB, swizzled
  int w = threadIdx.x >> 6, l = threadIdx.x & 63;
  size_t g0 = (size_t)blockIdx.x*64 + w*16;
  int row = l >> 2, qc = l & 3;

  const u16* srcb = h1b + (g0 + row)*256;
  f32x4 v[16];
#pragma unroll
  for (int m = 0; m < 16; ++m){
    uint2 p = *(const uint2*)&srcb[m*16 + qc*4];
    v[m][0] = lo_bits(p.x);
    v[m][1] = hi_bits(p.x);
    v[m][2] = lo_bits(p.y);
    v[m][3] = hi_bits(p.y);
  }
  float sum = 0.f, sq = 0.f;
#pragma unroll
  for (int m = 0; m < 16; ++m){
#pragma unroll
    for (int i = 0; i < 4; ++i){ sum += v[m][i]; sq += v[m][i]*v[m][i]; }
  }
  sum += __shfl_xor(sum, 1); sq += __shfl_xor(sq, 1);
  sum += __shfl_xor(sum, 2); sq += __shfl_xor(sq, 2);
  float mu = sum / 256.f;
  float rs = rsqrtf(sq / 256.f - mu*mu + 1e-5f);
  u16* xw = xls[w];
  int rsw = (row & 7) << 3;    // 16B-granule XOR swizzle, u16 units
#pragma unroll
  for (int m = 0; m < 16; ++m){
    int cb = m*16 + qc*4;
    f32x4 gq = *(const f32x4*)&lng[cb];
    f32x4 bq = *(const f32x4*)&lnb[cb];
    f32x4 xn;
#pragma unroll
    for (int i = 0; i < 4; ++i) xn[i] = (v[m][i]-mu)*rs*gq[i] + bq[i];
    *(uint2*)&xw[(row*256 + cb) ^ rsw] = pack4(xn);
  }

  // proj: (16x256)@(256x128) MFMA
  int lk = l >> 4, r = l & 15;
  int rsw2 = (r & 7) << 3;
  f32x4 acc[8];
#pragma unroll
  for (int nt = 0; nt < 8; ++nt) acc[nt] = *(const f32x4*)&projb[nt*16 + lk*4];
#pragma unroll
  for (int kf = 0; kf < 8; ++kf){
    v8s b = *(const v8s*)&xw[(r*256 + kf*32 + lk*8) ^ rsw2];
#pragma unroll
    for (int nt = 0; nt < 8; ++nt){
      v8s a = *(const v8s*)&projWp[(((size_t)nt*8 + kf)*64 + l)*8];
      acc[nt] = __builtin_amdgcn_mfma_f32_16x16x32_bf16(a, b, acc[nt], 0, 0, 0);
    }
  }
  u16* pw = pls[w];
#pragma unroll
  for (int nt = 0; nt < 8; ++nt)
    *(uint2*)&pw[(r*128 + nt*16 + lk*4) ^ rsw2] = pack4(acc[nt]);

  // head1: (16x128)@(128x128) MFMA
  f32x4 acc2[8];
#pragma unroll
  for (int nt = 0; nt < 8; ++nt) acc2[nt] = *(const f32x4*)&hb1[nt*16 + lk*4];
#pragma unroll
  for (int kf = 0; kf < 4; ++kf){
    v8s b = *(const v8s*)&pw[(r*128 + kf*32 + lk*8) ^ rsw2];
#pragma unroll
    for (int nt = 0; nt < 8; ++nt){
      v8s a = *(const v8s*)&hW1p[(((size_t)nt*4 + kf)*64 + l)*8];
      acc2[nt] = __builtin_amdgcn_mfma_f32_16x16x32_bf16(a, b, acc2[nt], 0, 0, 0);
    }
  }
  // head2: relu + dot with hW2, reduce lanes sharing r
  float part = 0.f;
#pragma unroll
  for (int nt = 0; nt < 8; ++nt){
    f32x4 w2 = *(const f32x4*)&hW2[nt*16 + lk*4];
#pragma unroll
    for (int jj = 0; jj < 4; ++jj) part += fmaxf(acc2[nt][jj], 0.f) * w2[jj];
  }
  part += __shfl_xor(part, 16);
  part += __shfl_xor(part, 32);
  if (l < 16) qout[g0 + l] = part + hb2[0];
}

// ---------------- AR blend --------------------------------------------------------
__global__ __launch_bounds__(512) void k_blend(const float* qout, float* out)
{
  int b = threadIdx.x;
  float pred = 0.f;
  for (int t0 = 0; t0 < TT; t0 += 16){
    float v[16];
#pragma unroll
    for (int i = 0; i < 16; ++i) v[i] = qout[(t0+i)*BB + b];
#pragma unroll
    for (int i = 0; i < 16; ++i){
      pred = (t0 + i == 0) ? v[i] : 0.8f*v[i] + 0.2f*pred;
      out[b*TT + t0 + i] = pred;
    }
  }
}

extern "C" void kernel_launch(void* const* d_in, const int* in_sizes, int n_in,
                              void* d_out, int out_size, void* d_ws, size_t ws_size,
                              hipStream_t stream) {
  const float* physical   = (const float*)d_in[0];
  const float* target_seq = (const float*)d_in[1];
  const float* enc_W1     = (const float*)d_in[2];
  const float* enc_b1     = (const float*)d_in[3];
  const float* enc_ln1_g  = (const float*)d_in[4];
  const float* enc_ln1_b  = (const float*)d_in[5];
  const float* enc_W2     = (const float*)d_in[6];
  const float* enc_b2     = (const float*)d_in[7];
  const float* enc_ln2_g  = (const float*)d_in[8];
  const float* enc_ln2_b  = (const float*)d_in[9];
  const float* Wih0       = (const float*)d_in[10];
  const float* Whh0       = (const float*)d_in[11];
  const float* bih0       = (const float*)d_in[12];
  const float* bhh0       = (const float*)d_in[13];
  const float* Wih1       = (const float*)d_in[14];
  const float* Whh1       = (const float*)d_in[15];
  const float* bih1       = (const float*)d_in[16];
  const float* bhh1       = (const float*)d_in[17];
  const float* ln_g       = (const float*)d_in[18];
  const float* ln_b       = (const float*)d_in[19];
  const float* proj_W     = (const float*)d_in[20];
  const float* proj_b     = (const float*)d_in[21];
  const float* head_W1    = (const float*)d_in[22];
  const float* head_b1    = (const float*)d_in[23];
  const float* head_W2    = (const float*)d_in[24];
  const float* head_b2    = (const float*)d_in[25];
  const float* init_input = (const float*)d_in[26];

  size_t off = 0;
  char* base = (char*)d_ws;
  auto carve = [&](size_t bytes) -> void* {
    void* p = base + off;
    off += (bytes + 255) & ~(size_t)255;
    return p;
  };
  u16*   o0pack  = (u16*)  carve((size_t)TT*32*8*64*8*2);     // 32 MB bf16 frag-packed
  u16*   h1b     = (u16*)  carve((size_t)TT*BB*256*2);        // 32 MB bf16
  u16*   z1p     = (u16*)  carve((size_t)TT*32*64*64*4*2);    // 128 MB bf16 C-frag
  float* qout    = (float*)carve((size_t)TT*BB*4);
  float* h0enc   = (float*)carve((size_t)BB*128*4);
  float* xs      = (float*)carve((size_t)TT*BB*4);
  u16*   W0p     = (u16*)  carve((size_t)2*512*128*2);
  u16*   W1ip    = (u16*)  carve((size_t)2*512*256*2);
  u16*   W1hp    = (u16*)  carve((size_t)2*512*128*2);
  u16*   projWp  = (u16*)  carve((size_t)128*256*2);
  u16*   hW1p    = (u16*)  carve((size_t)128*128*2);
  float* bias0   = (float*)carve(4096);
  float* bias1   = (float*)carve(4096);
  float* wv0     = (float*)carve(4096);

  k_prep<<<256, 256, 0, stream>>>(target_seq, init_input, Wih0, Whh0, bih0, bhh0,
                                  Wih1, Whh1, bih1, bhh1, proj_W, head_W1,
                                  xs, W0p, W1ip, W1hp, projWp, hW1p,
                                  bias0, bias1, wv0);
  k_enc<<<64, 256, 0, stream>>>(physical, enc_W1, enc_b1, enc_ln1_g, enc_ln1_b,
                                enc_W2, enc_b2, enc_ln2_g, enc_ln2_b, h0enc);
  k_l0<<<64, 512, 0, stream>>>(W0p, bias0, wv0, xs, h0enc, o0pack);
  k_zgemm<<<8192, 256, 0, stream>>>(W1ip, bias1, o0pack, z1p);
  k_l1<<<64, 512, 0, stream>>>(W1hp, z1p, h0enc, h1b);
  k_head<<<1024, 256, 0, stream>>>(h1b, ln_g, ln_b, projWp, proj_b,
                                   hW1p, head_b1, head_W2, head_b2, qout);
  k_blend<<<1, 512, 0, stream>>>(qout, (float*)d_out);
}

// Round 12
// 366.498 us; speedup vs baseline: 1.0907x; 1.0042x over previous
//
#include <hip/hip_runtime.h>
#include <hip/hip_bf16.h>

#define BB 512
#define TT 128

typedef unsigned short u16;
typedef short v8s __attribute__((ext_vector_type(8)));
typedef float f32x4 __attribute__((ext_vector_type(4)));

#define L2E  1.4426950408889634f
#define L2E2 2.8853900817779268f

__device__ __forceinline__ u16 f2bf(float x){
  union { float f; unsigned int u; } v; v.f = x;
  unsigned int r = (v.u + 0x7fffu + ((v.u >> 16) & 1u)) >> 16;
  return (u16)r;
}
__device__ __forceinline__ float lo_bits(unsigned u){
  union { unsigned int i; float f; } v; v.i = u << 16; return v.f;
}
__device__ __forceinline__ float hi_bits(unsigned u){
  union { unsigned int i; float f; } v; v.i = u & 0xffff0000u; return v.f;
}
// fast bf16 pack: RNE, matches f2bf
__device__ __forceinline__ uint2 pack4(f32x4 a){
  uint2 r;
  asm("v_cvt_pk_bf16_f32 %0, %1, %2" : "=v"(r.x) : "v"(a[0]), "v"(a[1]));
  asm("v_cvt_pk_bf16_f32 %0, %1, %2" : "=v"(r.y) : "v"(a[2]), "v"(a[3]));
  return r;
}
__device__ __forceinline__ float rcp_f(float x){ return __builtin_amdgcn_rcpf(x); }
__device__ __forceinline__ float exp2_f(float x){
  float r; asm("v_exp_f32 %0, %1" : "=v"(r) : "v"(x)); return r;
}
// inputs prescaled by log2e (i,f,o) and 2*log2e (g)
__device__ __forceinline__ float sigm2(float y){ return rcp_f(1.f + exp2_f(-y)); }
__device__ __forceinline__ float tanh2(float y){ return fmaf(2.f, sigm2(y), -1.f); }

// encoder-only (unscaled) helpers
__device__ __forceinline__ float tanh_f(float x){
  float e = __expf(-2.f * fabsf(x));
  float r = (1.f - e) * rcp_f(1.f + e);
  return copysignf(r, x);
}
// barrier that waits only LDS ops: global stores/loads stay in flight
__device__ __forceinline__ void bar_lds(){
  __builtin_amdgcn_sched_barrier(0);
  asm volatile("s_waitcnt lgkmcnt(0)" ::: "memory");
  __builtin_amdgcn_s_barrier();
  __builtin_amdgcn_sched_barrier(0);
}

// ---------------- prep (blocks 0..255) + encoder (blocks 256..319) ----------------
// prep: pack weights (prescaled by log2e) into MFMA frag order; frag layout
// (A and B identical): tile=j>>4, kf=k>>5, lane=(j&15)+16*((k&31)>>3), elem=k&7.
// enc: h0 = tanh(LN(relu(LN(x@W1^T+b1))@W2^T+b2)), 8 rows/block.
__global__ __launch_bounds__(256) void k_prep(
    const float* tseq, const float* init_in,
    const float* Wih0, const float* Whh0, const float* bih0, const float* bhh0,
    const float* Wih1, const float* Whh1, const float* bih1, const float* bhh1,
    const float* projW, const float* hW1,
    const float* phys, const float* eW1, const float* eb1, const float* eg1, const float* ebe1,
    const float* eW2, const float* eb2, const float* eg2, const float* ebe2, float* h0enc,
    float* xs, u16* W0p, u16* W1ip, u16* W1hp, u16* projWp, u16* hW1p,
    float* bias0, float* bias1, float* wv0)
{
  if (blockIdx.x >= 256){
    // ---------------- encoder role ----------------
    __shared__ float eL[8][256];
    int tid = threadIdx.x;
    int rr = tid >> 5, sub = tid & 31;
    int r = (blockIdx.x - 256) * 8 + rr;
    float x[16];
#pragma unroll
    for (int k = 0; k < 16; ++k) x[k] = phys[r*16 + k];
    float y[8];
#pragma unroll
    for (int jj = 0; jj < 8; ++jj){
      int j = sub*8 + jj;
      float s = eb1[j];
#pragma unroll
      for (int k = 0; k < 16; ++k) s += x[k] * eW1[j*16 + k];
      y[jj] = s;
    }
    float sum = 0.f, sq = 0.f;
#pragma unroll
    for (int jj = 0; jj < 8; ++jj){ sum += y[jj]; sq += y[jj]*y[jj]; }
#pragma unroll
    for (int m = 16; m >= 1; m >>= 1){ sum += __shfl_xor(sum, m, 32); sq += __shfl_xor(sq, m, 32); }
    float mu = sum / 256.f;
    float rs = rsqrtf(sq / 256.f - mu*mu + 1e-5f);
#pragma unroll
    for (int jj = 0; jj < 8; ++jj){
      int j = sub*8 + jj;
      eL[rr][j] = fmaxf((y[jj] - mu) * rs * eg1[j] + ebe1[j], 0.f);
    }
    __syncthreads();
    float y2[4];
#pragma unroll
    for (int jj = 0; jj < 4; ++jj){
      int j2 = sub*4 + jj;
      float s = eb2[j2];
      const float* wrow = eW2 + j2*256;
      for (int k = 0; k < 256; k += 4)
        s += eL[rr][k]*wrow[k] + eL[rr][k+1]*wrow[k+1] + eL[rr][k+2]*wrow[k+2] + eL[rr][k+3]*wrow[k+3];
      y2[jj] = s;
    }
    sum = 0.f; sq = 0.f;
#pragma unroll
    for (int jj = 0; jj < 4; ++jj){ sum += y2[jj]; sq += y2[jj]*y2[jj]; }
#pragma unroll
    for (int m = 16; m >= 1; m >>= 1){ sum += __shfl_xor(sum, m, 32); sq += __shfl_xor(sq, m, 32); }
    mu = sum / 128.f;
    rs = rsqrtf(sq / 128.f - mu*mu + 1e-5f);
#pragma unroll
    for (int jj = 0; jj < 4; ++jj){
      int j2 = sub*4 + jj;
      h0enc[r*128 + j2] = tanh_f((y2[jj]-mu)*rs*eg2[j2] + ebe2[j2]);
    }
    return;
  }
  // ---------------- prep role ----------------
  int tid = blockIdx.x * blockDim.x + threadIdx.x;
  int stride = 256 * blockDim.x;
  for (int i = tid; i < TT*BB; i += stride){
    int t = i / BB, b = i % BB;
    xs[i] = (t == 0) ? init_in[0] : tseq[b*TT + (t-1)];
  }
  for (int i = tid; i < 2*512*128; i += stride){
    int d = i / (512*128), r = i % (512*128);
    int j = r / 128, k = r % 128;
    float sc = ((j >> 7) == 2) ? L2E2 : L2E;
    int dst = ((((d*32 + (j>>4))*4 + (k>>5))*64) + ((j&15) + 16*((k&31)>>3)))*8 + (k&7);
    W0p[dst]  = f2bf(Whh0[i] * sc);
    W1hp[dst] = f2bf(Whh1[i] * sc);
  }
  for (int i = tid; i < 2*512*256; i += stride){
    int d = i / (512*256), r = i % (512*256);
    int j = r / 256, k = r % 256;
    float sc = ((j >> 7) == 2) ? L2E2 : L2E;
    int dst = ((((d*32 + (j>>4))*8 + (k>>5))*64) + ((j&15) + 16*((k&31)>>3)))*8 + (k&7);
    W1ip[dst] = f2bf(Wih1[i] * sc);
  }
  for (int i = tid; i < 128*256; i += stride){
    int j = i / 256, k = i % 256;
    int dst = ((((j>>4)*8 + (k>>5))*64) + ((j&15) + 16*((k&31)>>3)))*8 + (k&7);
    projWp[dst] = f2bf(projW[i]);
  }
  for (int i = tid; i < 128*128; i += stride){
    int j = i / 128, k = i % 128;
    int dst = ((((j>>4)*4 + (k>>5))*64) + ((j&15) + 16*((k&31)>>3)))*8 + (k&7);
    hW1p[dst] = f2bf(hW1[i]);
  }
  for (int i = tid; i < 2*512; i += stride){
    float sc = (((i & 511) >> 7) == 2) ? L2E2 : L2E;
    bias0[i] = (bih0[i] + bhh0[i]) * sc;
    bias1[i] = (bih1[i] + bhh1[i]) * sc;
    wv0[i]   = Wih0[i] * sc;
  }
}

// ---------------- layer0 recurrence (round-4 config: issue-bound, compiler-sched) -
__global__ __launch_bounds__(512) void k_l0(
    const u16* W0p, const float* bias0, const float* wv0, const float* xs,
    const float* h0enc, u16* o0pack)
{
  __shared__ __align__(16) u16 Xb[2][4][512];
  __shared__ __align__(16) float xl[TT*16];
  int bx = blockIdx.x;
  int tile = bx & 31, d = bx >> 5;
  int tid = threadIdx.x, w = tid >> 6, l = tid & 63;
  int r0 = tile * 16, lrow = l & 15, lk = l >> 4;

  for (int i = tid; i < TT*16; i += 512){
    int t = i >> 4, r = i & 15;
    xl[i] = xs[t*BB + r0 + r];
  }
  if (tid < 256){
    int kf = tid >> 6, ll = tid & 63;
    const float* src = h0enc + (r0 + (ll & 15))*128 + kf*32 + 8*(ll >> 4);
    u16* dstp = &Xb[0][kf][ll*8];
#pragma unroll
    for (int i = 0; i < 8; ++i) dstp[i] = f2bf(src[i]);
  }

  const u16* Wb = W0p + (size_t)d*32*4*512;
  v8s wa[4][4];
#pragma unroll
  for (int q = 0; q < 4; ++q)
#pragma unroll
    for (int kf = 0; kf < 4; ++kf)
      wa[q][kf] = *(const v8s*)(Wb + (size_t)(((w + 8*q)*4 + kf)*64 + l)*8);

  float bias[4][4], wv[4][4];
#pragma unroll
  for (int q = 0; q < 4; ++q){
    int tq = w + 8*q;
#pragma unroll
    for (int jj = 0; jj < 4; ++jj){
      int j = tq*16 + 4*lk + jj;
      bias[q][jj] = bias0[d*512 + j];
      wv[q][jj]   = wv0[d*512 + j];
    }
  }
  float c[4] = {0.f,0.f,0.f,0.f};
  int jout = w*16 + 4*lk;
  int kfx = jout >> 5;
  int sl  = lrow + 16*((jout & 31) >> 3);
  int eb  = jout & 7;
  int kfo = 4*d + kfx;
  __syncthreads();

#pragma unroll 2
  for (int t = 0; t < TT; ++t){
    int cur = t & 1, nxt = cur ^ 1;
    v8s bfr[4];
#pragma unroll
    for (int kf = 0; kf < 4; ++kf) bfr[kf] = *(const v8s*)&Xb[cur][kf][l*8];
    float xv = xl[t*16 + lrow];
    f32x4 acc[4];
#pragma unroll
    for (int q = 0; q < 4; ++q)
#pragma unroll
      for (int jj = 0; jj < 4; ++jj)
        acc[q][jj] = fmaf(xv, wv[q][jj], bias[q][jj]);
#pragma unroll
    for (int kf = 0; kf < 4; ++kf)
#pragma unroll
      for (int q = 0; q < 4; ++q)
        acc[q] = __builtin_amdgcn_mfma_f32_16x16x32_bf16(wa[q][kf], bfr[kf], acc[q], 0, 0, 0);
    f32x4 hv;
#pragma unroll
    for (int jj = 0; jj < 4; ++jj){
      float si = sigm2(acc[0][jj]);
      float sf = sigm2(acc[1][jj]);
      float tg = tanh2(acc[2][jj]);
      float so = sigm2(acc[3][jj]);
      float cn = fmaf(sf, c[jj], si*tg);
      c[jj] = cn;
      float s2 = sigm2(L2E2 * cn);
      hv[jj] = so * fmaf(2.f, s2, -1.f);
    }
    uint2 hp = pack4(hv);
    *(uint2*)&Xb[nxt][kfx][sl*8 + eb] = hp;
    size_t off = ((((size_t)t*32 + tile)*8 + kfo)*64 + sl)*8 + eb;
    *(uint2*)&o0pack[off] = hp;     // fire-and-forget
    bar_lds();
  }
}

// ---------------- Z1 = bias1 + o0 @ Wih1^T, W staged via LDS (shared by 4 waves) --
// grid: t(128) x bg(8: 4-btile groups) x nc(8: 8-nt chunks) = 8192 blocks
__global__ __launch_bounds__(256) void k_zgemm(
    const u16* W1ip, const float* bias1p, const u16* o0pack, u16* z1p)
{
  __shared__ __align__(16) u16 Wl[8][4][64][8];   // 32 KB: [nt][kq][lane][e]
  int bx = blockIdx.x;
  int nc = bx & 7, bg = (bx >> 3) & 7, t = bx >> 6;
  int tid = threadIdx.x;
  int w = tid >> 6, l = tid & 63;
  int btile = bg*4 + w;
  int lk4 = (l >> 4) * 4;
  const u16* Wsrc = W1ip + (size_t)nc*8*8*64*8;   // nt-major contiguous chunk
  u16* WlF = &Wl[0][0][0][0];

  v8s bfrag[8];
#pragma unroll
  for (int kf = 0; kf < 8; ++kf)
    bfrag[kf] = *(const v8s*)&o0pack[((((size_t)t*32 + btile)*8 + kf)*64 + l)*8];
  f32x4 acc[8];
#pragma unroll
  for (int nt = 0; nt < 8; ++nt){
    int ntg = nc*8 + nt;
    acc[nt] = *(const f32x4*)&bias1p[(ntg >> 5)*512 + (ntg & 31)*16 + lk4];
  }
#pragma unroll
  for (int ph = 0; ph < 2; ++ph){
    if (ph) __syncthreads();          // protect buffer reuse
#pragma unroll
    for (int i = 0; i < 8; ++i){
      int cid = i*256 + tid;          // coalesced 16B chunks
      int nt = cid >> 8, r = cid & 255;
      v8s v = *(const v8s*)&Wsrc[(size_t)(nt*8 + ph*4)*512 + r*8];
      *(v8s*)&WlF[cid*8] = v;
    }
    __syncthreads();
#pragma unroll
    for (int kq = 0; kq < 4; ++kq){
      int kf = ph*4 + kq;
#pragma unroll
      for (int nt = 0; nt < 8; ++nt){
        v8s a = *(const v8s*)&Wl[nt][kq][l][0];
        acc[nt] = __builtin_amdgcn_mfma_f32_16x16x32_bf16(a, bfrag[kf], acc[nt], 0, 0, 0);
      }
    }
  }
#pragma unroll
  for (int nt = 0; nt < 8; ++nt){
    int ntg = nc*8 + nt;
    uint2 zp = pack4(acc[nt]);
    *(uint2*)&z1p[((((size_t)t*32 + btile)*64 + ntg)*64 + l)*4] = zp;
  }
}

// ---------------- layer1 recurrence (round-4 config), depth-2 Z prefetch ----------
__global__ __launch_bounds__(512) void k_l1(
    const u16* W1hp, const u16* z1p, const float* h0enc, u16* h1b)
{
  __shared__ __align__(16) u16 Xh[2][4][512];
  int bx = blockIdx.x;
  int tile = bx & 31, d = bx >> 5;
  int tid = threadIdx.x, w = tid >> 6, l = tid & 63;
  int r0 = tile * 16, lrow = l & 15, lk = l >> 4;

  if (tid < 256){
    int kf = tid >> 6, ll = tid & 63;
    const float* src = h0enc + (r0 + (ll & 15))*128 + kf*32 + 8*(ll >> 4);
    u16* dstp = &Xh[0][kf][ll*8];
#pragma unroll
    for (int i = 0; i < 8; ++i) dstp[i] = f2bf(src[i]);
  }

  const u16* Wh = W1hp + (size_t)d*32*4*512;
  v8s wh[4][4];
#pragma unroll
  for (int q = 0; q < 4; ++q)
#pragma unroll
    for (int kf = 0; kf < 4; ++kf)
      wh[q][kf] = *(const v8s*)(Wh + (size_t)(((w + 8*q)*4 + kf)*64 + l)*8);

  float c[4] = {0.f,0.f,0.f,0.f};
  int jout = w*16 + 4*lk;
  int kfx = jout >> 5;
  int sl  = lrow + 16*((jout & 31) >> 3);
  int eb  = jout & 7;
  int zcol = d*32 + w;    // base ntg for q=0

  uint2 zr[4], zn[4];
#pragma unroll
  for (int q = 0; q < 4; ++q)
    zr[q] = *(const uint2*)&z1p[(((size_t)tile*64 + zcol + 8*q)*64 + l)*4];
#pragma unroll
  for (int q = 0; q < 4; ++q)
    zn[q] = *(const uint2*)&z1p[((((size_t)1*32 + tile)*64 + zcol + 8*q)*64 + l)*4];
  __syncthreads();

#pragma unroll 2
  for (int t = 0; t < TT; ++t){
    int cur = t & 1, nxt = cur ^ 1;
    v8s bh[4];
#pragma unroll
    for (int kf = 0; kf < 4; ++kf) bh[kf] = *(const v8s*)&Xh[cur][kf][l*8];
    f32x4 acc[4];
#pragma unroll
    for (int q = 0; q < 4; ++q){
      acc[q][0] = lo_bits(zr[q].x);
      acc[q][1] = hi_bits(zr[q].x);
      acc[q][2] = lo_bits(zr[q].y);
      acc[q][3] = hi_bits(zr[q].y);
    }
#pragma unroll
    for (int kf = 0; kf < 4; ++kf)
#pragma unroll
      for (int q = 0; q < 4; ++q)
        acc[q] = __builtin_amdgcn_mfma_f32_16x16x32_bf16(wh[q][kf], bh[kf], acc[q], 0, 0, 0);
    f32x4 hv;
#pragma unroll
    for (int jj = 0; jj < 4; ++jj){
      float si = sigm2(acc[0][jj]);
      float sf = sigm2(acc[1][jj]);
      float tg = tanh2(acc[2][jj]);
      float so = sigm2(acc[3][jj]);
      float cn = fmaf(sf, c[jj], si*tg);
      c[jj] = cn;
      float s2 = sigm2(L2E2 * cn);
      hv[jj] = so * fmaf(2.f, s2, -1.f);
    }
    uint2 hp = pack4(hv);
    *(uint2*)&Xh[nxt][kfx][sl*8 + eb] = hp;
    int hidx = ((t*BB + r0 + lrow) << 8) + (d << 7) + jout;
    *(uint2*)&h1b[hidx] = hp;       // fire-and-forget
#pragma unroll
    for (int q = 0; q < 4; ++q) zr[q] = zn[q];
    int tp = (t + 2 < TT) ? t + 2 : TT - 1;
#pragma unroll
    for (int q = 0; q < 4; ++q)
      zn[q] = *(const uint2*)&z1p[((((size_t)tp*32 + tile)*64 + zcol + 8*q)*64 + l)*4];
    bar_lds();
  }
}

// ---------------- head: LN -> proj -> relu head1 -> head2 via MFMA ---------------
__global__ __launch_bounds__(256) void k_head(
    const u16* h1b, const float* lng, const float* lnb,
    const u16* projWp, const float* projb,
    const u16* hW1p, const float* hb1, const float* hW2, const float* hb2,
    float* qout)
{
  __shared__ __align__(16) u16 xls[4][16*256];  // 32 KB, swizzled
  __shared__ __align__(16) u16 pls[4][16*128];  // 16 KB, swizzled
  int w = threadIdx.x >> 6, l = threadIdx.x & 63;
  size_t g0 = (size_t)blockIdx.x*64 + w*16;
  int row = l >> 2, qc = l & 3;

  const u16* srcb = h1b + (g0 + row)*256;
  f32x4 v[16];
#pragma unroll
  for (int m = 0; m < 16; ++m){
    uint2 p = *(const uint2*)&srcb[m*16 + qc*4];
    v[m][0] = lo_bits(p.x);
    v[m][1] = hi_bits(p.x);
    v[m][2] = lo_bits(p.y);
    v[m][3] = hi_bits(p.y);
  }
  float sum = 0.f, sq = 0.f;
#pragma unroll
  for (int m = 0; m < 16; ++m){
#pragma unroll
    for (int i = 0; i < 4; ++i){ sum += v[m][i]; sq += v[m][i]*v[m][i]; }
  }
  sum += __shfl_xor(sum, 1); sq += __shfl_xor(sq, 1);
  sum += __shfl_xor(sum, 2); sq += __shfl_xor(sq, 2);
  float mu = sum / 256.f;
  float rs = rsqrtf(sq / 256.f - mu*mu + 1e-5f);
  u16* xw = xls[w];
  int rsw = (row & 7) << 3;    // 16B-granule XOR swizzle, u16 units
#pragma unroll
  for (int m = 0; m < 16; ++m){
    int cb = m*16 + qc*4;
    f32x4 gq = *(const f32x4*)&lng[cb];
    f32x4 bq = *(const f32x4*)&lnb[cb];
    f32x4 xn;
#pragma unroll
    for (int i = 0; i < 4; ++i) xn[i] = (v[m][i]-mu)*rs*gq[i] + bq[i];
    *(uint2*)&xw[(row*256 + cb) ^ rsw] = pack4(xn);
  }

  // proj: (16x256)@(256x128) MFMA
  int lk = l >> 4, r = l & 15;
  int rsw2 = (r & 7) << 3;
  f32x4 acc[8];
#pragma unroll
  for (int nt = 0; nt < 8; ++nt) acc[nt] = *(const f32x4*)&projb[nt*16 + lk*4];
#pragma unroll
  for (int kf = 0; kf < 8; ++kf){
    v8s b = *(const v8s*)&xw[(r*256 + kf*32 + lk*8) ^ rsw2];
#pragma unroll
    for (int nt = 0; nt < 8; ++nt){
      v8s a = *(const v8s*)&projWp[(((size_t)nt*8 + kf)*64 + l)*8];
      acc[nt] = __builtin_amdgcn_mfma_f32_16x16x32_bf16(a, b, acc[nt], 0, 0, 0);
    }
  }
  u16* pw = pls[w];
#pragma unroll
  for (int nt = 0; nt < 8; ++nt)
    *(uint2*)&pw[(r*128 + nt*16 + lk*4) ^ rsw2] = pack4(acc[nt]);

  // head1: (16x128)@(128x128) MFMA
  f32x4 acc2[8];
#pragma unroll
  for (int nt = 0; nt < 8; ++nt) acc2[nt] = *(const f32x4*)&hb1[nt*16 + lk*4];
#pragma unroll
  for (int kf = 0; kf < 4; ++kf){
    v8s b = *(const v8s*)&pw[(r*128 + kf*32 + lk*8) ^ rsw2];
#pragma unroll
    for (int nt = 0; nt < 8; ++nt){
      v8s a = *(const v8s*)&hW1p[(((size_t)nt*4 + kf)*64 + l)*8];
      acc2[nt] = __builtin_amdgcn_mfma_f32_16x16x32_bf16(a, b, acc2[nt], 0, 0, 0);
    }
  }
  // head2: relu + dot with hW2, reduce lanes sharing r
  float part = 0.f;
#pragma unroll
  for (int nt = 0; nt < 8; ++nt){
    f32x4 w2 = *(const f32x4*)&hW2[nt*16 + lk*4];
#pragma unroll
    for (int jj = 0; jj < 4; ++jj) part += fmaxf(acc2[nt][jj], 0.f) * w2[jj];
  }
  part += __shfl_xor(part, 16);
  part += __shfl_xor(part, 32);
  if (l < 16) qout[g0 + l] = part + hb2[0];
}

// ---------------- AR blend --------------------------------------------------------
__global__ __launch_bounds__(512) void k_blend(const float* qout, float* out)
{
  int b = threadIdx.x;
  float pred = 0.f;
  for (int t0 = 0; t0 < TT; t0 += 16){
    float v[16];
#pragma unroll
    for (int i = 0; i < 16; ++i) v[i] = qout[(t0+i)*BB + b];
#pragma unroll
    for (int i = 0; i < 16; ++i){
      pred = (t0 + i == 0) ? v[i] : 0.8f*v[i] + 0.2f*pred;
      out[b*TT + t0 + i] = pred;
    }
  }
}

extern "C" void kernel_launch(void* const* d_in, const int* in_sizes, int n_in,
                              void* d_out, int out_size, void* d_ws, size_t ws_size,
                              hipStream_t stream) {
  const float* physical   = (const float*)d_in[0];
  const float* target_seq = (const float*)d_in[1];
  const float* enc_W1     = (const float*)d_in[2];
  const float* enc_b1     = (const float*)d_in[3];
  const float* enc_ln1_g  = (const float*)d_in[4];
  const float* enc_ln1_b  = (const float*)d_in[5];
  const float* enc_W2     = (const float*)d_in[6];
  const float* enc_b2     = (const float*)d_in[7];
  const float* enc_ln2_g  = (const float*)d_in[8];
  const float* enc_ln2_b  = (const float*)d_in[9];
  const float* Wih0       = (const float*)d_in[10];
  const float* Whh0       = (const float*)d_in[11];
  const float* bih0       = (const float*)d_in[12];
  const float* bhh0       = (const float*)d_in[13];
  const float* Wih1       = (const float*)d_in[14];
  const float* Whh1       = (const float*)d_in[15];
  const float* bih1       = (const float*)d_in[16];
  const float* bhh1       = (const float*)d_in[17];
  const float* ln_g       = (const float*)d_in[18];
  const float* ln_b       = (const float*)d_in[19];
  const float* proj_W     = (const float*)d_in[20];
  const float* proj_b     = (const float*)d_in[21];
  const float* head_W1    = (const float*)d_in[22];
  const float* head_b1    = (const float*)d_in[23];
  const float* head_W2    = (const float*)d_in[24];
  const float* head_b2    = (const float*)d_in[25];
  const float* init_input = (const float*)d_in[26];

  size_t off = 0;
  char* base = (char*)d_ws;
  auto carve = [&](size_t bytes) -> void* {
    void* p = base + off;
    off += (bytes + 255) & ~(size_t)255;
    return p;
  };
  u16*   o0pack  = (u16*)  carve((size_t)TT*32*8*64*8*2);     // 32 MB bf16 frag-packed
  u16*   h1b     = (u16*)  carve((size_t)TT*BB*256*2);        // 32 MB bf16
  u16*   z1p     = (u16*)  carve((size_t)TT*32*64*64*4*2);    // 128 MB bf16 C-frag
  float* qout    = (float*)carve((size_t)TT*BB*4);
  float* h0enc   = (float*)carve((size_t)BB*128*4);
  float* xs      = (float*)carve((size_t)TT*BB*4);
  u16*   W0p     = (u16*)  carve((size_t)2*512*128*2);
  u16*   W1ip    = (u16*)  carve((size_t)2*512*256*2);
  u16*   W1hp    = (u16*)  carve((size_t)2*512*128*2);
  u16*   projWp  = (u16*)  carve((size_t)128*256*2);
  u16*   hW1p    = (u16*)  carve((size_t)128*128*2);
  float* bias0   = (float*)carve(4096);
  float* bias1   = (float*)carve(4096);
  float* wv0     = (float*)carve(4096);

  k_prep<<<320, 256, 0, stream>>>(target_seq, init_input, Wih0, Whh0, bih0, bhh0,
                                  Wih1, Whh1, bih1, bhh1, proj_W, head_W1,
                                  physical, enc_W1, enc_b1, enc_ln1_g, enc_ln1_b,
                                  enc_W2, enc_b2, enc_ln2_g, enc_ln2_b, h0enc,
                                  xs, W0p, W1ip, W1hp, projWp, hW1p,
                                  bias0, bias1, wv0);
  k_l0<<<64, 512, 0, stream>>>(W0p, bias0, wv0, xs, h0enc, o0pack);
  k_zgemm<<<8192, 256, 0, stream>>>(W1ip, bias1, o0pack, z1p);
  k_l1<<<64, 512, 0, stream>>>(W1hp, z1p, h0enc, h1b);
  k_head<<<1024, 256, 0, stream>>>(h1b, ln_g, ln_b, projWp, proj_b,
                                   hW1p, head_b1, head_W2, head_b2, qout);
  k_blend<<<1, 512, 0, stream>>>(qout, (float*)d_out);
}